// Round 8
// baseline (27.156 us; speedup 1.0000x reference)
//
#include <hip/hip_runtime.h>

typedef float f32x4 __attribute__((ext_vector_type(4)));

#define A      8                 // anchors per wave (shared scan)
#define BLOCK  256               // 4 waves per block

// Fused triplet miner: 8 CONSECUTIVE ANCHORS PER WAVE.
//  Phase A: wave scans labels once (int4/lane = 256 labels/iter, 2-deep
//    prefetch); per chunk each pending anchor resolves pos/neg via nibble
//    mask + ballot. Label traffic amortized 8x vs wave-per-anchor.
//  Phase B: same wave writes 3 rows per anchor (anchor/pos/neg, 512 B each)
//    with non-temporal stores (write-once stream, keep L2 for emb/labels).
__global__ void __launch_bounds__(BLOCK) triplet_fused_kernel(
    const int* __restrict__ labels,
    const f32x4* __restrict__ emb,    // [N][D4]
    f32x4* __restrict__ out,          // [3][N][D4]
    float* __restrict__ valid_out,    // [N]
    int N, int D4) {

    int lane = threadIdx.x & 63;
    int wid  = (blockIdx.x * BLOCK + threadIdx.x) >> 6;
    int i0   = wid * A;               // first anchor of this wave
    if (i0 >= N) return;

    const int4* lab4 = (const int4*)labels;
    int nq = N >> 2;                  // int4 chunks (N % 4 == 0)

    // Anchor labels (wave-uniform; i0 % 8 == 0 so 4-aligned)
    int my[A];
    {
        int4 m0 = lab4[min(i0 >> 2,       nq - 1)];
        int4 m1 = lab4[min((i0 >> 2) + 1, nq - 1)];
        my[0] = m0.x; my[1] = m0.y; my[2] = m0.z; my[3] = m0.w;
        my[4] = m1.x; my[5] = m1.y; my[6] = m1.z; my[7] = m1.w;
    }

    int p[A], ng[A];
    #pragma unroll
    for (int k = 0; k < A; ++k) { p[k] = -1; ng[k] = -1; }

    // Intra-group region: labels at i0+1..i0+7 are my[1..7] (wave-uniform).
    #pragma unroll
    for (int k = 0; k < A - 1; ++k) {
        #pragma unroll
        for (int m = k + 1; m < A; ++m) {
            if (i0 + m < N) {
                if (p[k]  < 0 && my[m] == my[k]) p[k]  = i0 + m;
                if (ng[k] < 0 && my[m] != my[k]) ng[k] = i0 + m;
            }
        }
    }

    unsigned pending = 0;
    #pragma unroll
    for (int k = 0; k < A; ++k)
        if (i0 + k < N && (p[k] < 0 || ng[k] < 0)) pending |= (1u << k);

    // Main shared scan over j >= i0+8 (all j > every anchor; no j>i masks).
    int kbase = (i0 + A) >> 2;        // exact (i0+8 is 4-aligned)
    if (pending && kbase < nq) {
        int4 c0 = lab4[min(kbase +      lane, nq - 1)];
        int4 c1 = lab4[min(kbase + 64 + lane, nq - 1)];

        while (true) {
            int4 c2 = lab4[min(kbase + 128 + lane, nq - 1)];
            bool valid = (kbase + lane) < nq;

            #pragma unroll
            for (int k = 0; k < A; ++k) {
                if (!(pending & (1u << k))) continue;      // wave-uniform
                unsigned ms = (c0.x == my[k] ? 1u : 0u)
                            | (c0.y == my[k] ? 2u : 0u)
                            | (c0.z == my[k] ? 4u : 0u)
                            | (c0.w == my[k] ? 8u : 0u);
                if (p[k] < 0) {
                    unsigned long long bs = __ballot(valid && ms != 0u);
                    if (bs) {
                        int ls = (int)__ffsll(bs) - 1;
                        unsigned m = __shfl(ms, ls);
                        p[k] = ((kbase + ls) << 2) + (__ffs(m) - 1);
                    }
                }
                if (ng[k] < 0) {
                    unsigned long long bd = __ballot(valid && ms != 0xFu);
                    if (bd) {
                        int ls = (int)__ffsll(bd) - 1;
                        unsigned m = __shfl(ms, ls);
                        ng[k] = ((kbase + ls) << 2) + (__ffs(m ^ 0xFu) - 1);
                    }
                }
                if (p[k] >= 0 && ng[k] >= 0) pending &= ~(1u << k);
            }

            kbase += 64;
            if (!pending || kbase >= nq) break;
            c0 = c1; c1 = c2;
        }
    }

    // Valid flags: lanes 0..7 write i0..i0+7 (coalesced 32 B).
    if (lane < A && i0 + lane < N) {
        int k = lane;
        valid_out[i0 + k] = (p[k] >= 0 && ng[k] >= 0) ? 1.0f : 0.0f;
    }

    // Write 3 rows per anchor. Lanes 0-31: anchor row + neg row;
    // lanes 32-63: pos row. Each 32-lane pass = 512 B coalesced.
    size_t ND4 = (size_t)N * D4;
    int t  = lane >> 5;
    int d4 = lane & 31;               // D4 == 32: one f32x4 per lane

    #pragma unroll
    for (int k = 0; k < A; ++k) {
        int i = i0 + k;
        if (i >= N) break;
        float v  = (p[k] >= 0 && ng[k] >= 0) ? 1.0f : 0.0f;
        int   ps = (p[k]  >= 0) ? p[k]  : 0;  // index irrelevant when invalid
        int   ns = (ng[k] >= 0) ? ng[k] : 0;

        int src = (t == 0) ? i : ps;
        f32x4 e = emb[(size_t)src * D4 + d4];
        __builtin_nontemporal_store(e * v,
            &out[(size_t)t * ND4 + (size_t)i * D4 + d4]);

        if (lane < 32) {
            f32x4 e2 = emb[(size_t)ns * D4 + d4];
            __builtin_nontemporal_store(e2 * v,
                &out[2 * ND4 + (size_t)i * D4 + d4]);
        }
    }
}

extern "C" void kernel_launch(void* const* d_in, const int* in_sizes, int n_in,
                              void* d_out, int out_size, void* d_ws, size_t ws_size,
                              hipStream_t stream) {
    const float* emb    = (const float*)d_in[0];
    const int*   labels = (const int*)d_in[1];   // harness passes integers as int32

    int N  = in_sizes[1];            // 16384
    int D  = in_sizes[0] / N;        // 128
    int D4 = D / 4;                  // 32

    float* out       = (float*)d_out;
    float* valid_out = out + (size_t)3 * N * D;  // tail of d_out: [N] valid mask

    int waves = (N + A - 1) / A;
    int nblk  = (waves * 64 + BLOCK - 1) / BLOCK;
    triplet_fused_kernel<<<nblk, BLOCK, 0, stream>>>(
        labels, (const f32x4*)emb, (f32x4*)out, valid_out, N, D4);
}

// Round 9
// 15.743 us; speedup vs baseline: 1.7249x; 1.7249x over previous
//
#include <hip/hip_runtime.h>

typedef float f32x4 __attribute__((ext_vector_type(4)));

#define BLOCK 256   // 4 waves per block, one anchor per wave

// Fused triplet miner: ONE WAVE per anchor, minimized serial chain.
//  - lane reads 8 CONTIGUOUS labels (2x int4 at chunks kbase+2*lane, +1),
//    512 labels/iteration, 2-deep register prefetch.
//  - per iteration: 8 compares -> 8-bit mask -> TWO ballots -> branch.
//    (mask bit order == j order, so first-match ordering is preserved)
//  - exact pos/neg indices resolved AFTER the loop from recorded ballots
//    (L1-hot reloads) -- no __shfl in the hot loop.
//  - anchor emb row loaded BEFORE mining (latency hidden under the scan);
//    pos+neg rows fetched with one combined instruction afterwards.
//  - 25 MB output written with non-temporal stores.
__global__ void __launch_bounds__(BLOCK) triplet_fused_kernel(
    const int* __restrict__ labels,
    const f32x4* __restrict__ emb,    // [N][32]
    f32x4* __restrict__ out,          // [3][N][32]
    float* __restrict__ valid_out,    // [N]
    int N) {

    const int D4 = 32;
    int lane = threadIdx.x & 63;
    int i = blockIdx.x * (BLOCK >> 6) + (threadIdx.x >> 6);   // anchor (wave-uniform)
    if (i >= N) return;

    // Early independent loads: anchor label + anchor embedding row.
    int d4 = lane & 31;
    f32x4 ea = emb[(size_t)i * D4 + d4];   // all lanes read row i (L1 broadcast)
    int my = labels[i];

    const int4* lab4 = (const int4*)labels;
    int nq = N >> 2;                       // N % 4 == 0

    int kb0 = (i + 1) >> 2;                // first chunk containing j > i

    // First-iteration validity mask: only lane 0's first chunk can hold j <= i.
    unsigned mv_first = 0xFFu;
    if (lane == 0) {
        int j0 = kb0 << 2;
        int nclr = i - j0 + 1;             // leading labels with j <= i (0..3)
        if (nclr > 0) mv_first &= (0xFFu << nclr);
    }

    int kbase = kb0;
    bool fp = false, fn = false;
    unsigned long long balp = 0, baln = 0;
    int basep = 0, basen = 0;

    // 2-deep prefetch (clamped addresses; masked by mv in processing).
    int4 a0 = lab4[min(kbase + 2 * lane,     nq - 1)];
    int4 b0 = lab4[min(kbase + 2 * lane + 1, nq - 1)];
    int4 a1 = lab4[min(kbase + 128 + 2 * lane,     nq - 1)];
    int4 b1 = lab4[min(kbase + 128 + 2 * lane + 1, nq - 1)];

    unsigned mv_iter = mv_first;
    if (kbase < nq) {
        while (true) {
            int4 a2 = lab4[min(kbase + 256 + 2 * lane,     nq - 1)];
            int4 b2 = lab4[min(kbase + 256 + 2 * lane + 1, nq - 1)];

            int kq0 = kbase + 2 * lane, kq1 = kq0 + 1;
            unsigned mv = mv_iter;
            if (kq0 >= nq)      mv = 0;
            else if (kq1 >= nq) mv &= 0x0Fu;

            unsigned ms = (a0.x == my ?   1u : 0u) | (a0.y == my ?   2u : 0u)
                        | (a0.z == my ?   4u : 0u) | (a0.w == my ?   8u : 0u)
                        | (b0.x == my ?  16u : 0u) | (b0.y == my ?  32u : 0u)
                        | (b0.z == my ?  64u : 0u) | (b0.w == my ? 128u : 0u);

            unsigned long long bp = __ballot((ms & mv)  != 0u);
            unsigned long long bn = __ballot((~ms & mv) != 0u);
            if (!fp && bp) { fp = true; balp = bp; basep = kbase; }
            if (!fn && bn) { fn = true; baln = bn; basen = kbase; }

            kbase += 128;
            if ((fp && fn) || kbase >= nq) break;
            a0 = a1; b0 = b1; a1 = a2; b1 = b2;
            mv_iter = 0xFFu;
        }
    }

    // Resolve exact indices off the critical loop (L1-hot reloads).
    int p = 0, ng = 0;
    if (fp) {
        int ls  = (int)__ffsll(balp) - 1;
        int c0i = basep + 2 * ls;
        int4 ca = lab4[c0i];
        int4 cb = lab4[min(c0i + 1, nq - 1)];
        unsigned ms = (ca.x == my ?   1u : 0u) | (ca.y == my ?   2u : 0u)
                    | (ca.z == my ?   4u : 0u) | (ca.w == my ?   8u : 0u)
                    | (cb.x == my ?  16u : 0u) | (cb.y == my ?  32u : 0u)
                    | (cb.z == my ?  64u : 0u) | (cb.w == my ? 128u : 0u);
        unsigned mvr = 0;
        #pragma unroll
        for (int b = 0; b < 8; ++b) {
            int j = (c0i << 2) + b;
            if (j > i && j < N) mvr |= (1u << b);
        }
        p = (c0i << 2) + (__ffs(ms & mvr) - 1);
    }
    if (fn) {
        int ls  = (int)__ffsll(baln) - 1;
        int c0i = basen + 2 * ls;
        int4 ca = lab4[c0i];
        int4 cb = lab4[min(c0i + 1, nq - 1)];
        unsigned ms = (ca.x == my ?   1u : 0u) | (ca.y == my ?   2u : 0u)
                    | (ca.z == my ?   4u : 0u) | (ca.w == my ?   8u : 0u)
                    | (cb.x == my ?  16u : 0u) | (cb.y == my ?  32u : 0u)
                    | (cb.z == my ?  64u : 0u) | (cb.w == my ? 128u : 0u);
        unsigned mvr = 0;
        #pragma unroll
        for (int b = 0; b < 8; ++b) {
            int j = (c0i << 2) + b;
            if (j > i && j < N) mvr |= (1u << b);
        }
        ng = (c0i << 2) + (__ffs(~ms & mvr) - 1);
    }

    float v = (fp && fn) ? 1.0f : 0.0f;
    if (lane == 0) valid_out[i] = v;

    // Combined gather: lanes<32 -> neg row, lanes>=32 -> pos row (one instr).
    size_t ND4 = (size_t)N * D4;
    int gsrc = (lane < 32) ? ng : p;
    f32x4 eg = emb[(size_t)gsrc * D4 + d4];

    // Pass 1: lanes<32 store anchor row (t=0), lanes>=32 store pos row (t=1).
    int   t  = lane >> 5;
    f32x4 r0 = (lane < 32) ? ea : eg;
    __builtin_nontemporal_store(r0 * v, &out[(size_t)t * ND4 + (size_t)i * D4 + d4]);

    // Pass 2: lanes<32 store neg row (t=2).
    if (lane < 32)
        __builtin_nontemporal_store(eg * v, &out[2 * ND4 + (size_t)i * D4 + d4]);
}

extern "C" void kernel_launch(void* const* d_in, const int* in_sizes, int n_in,
                              void* d_out, int out_size, void* d_ws, size_t ws_size,
                              hipStream_t stream) {
    const float* emb    = (const float*)d_in[0];
    const int*   labels = (const int*)d_in[1];   // harness passes integers as int32

    int N = in_sizes[1];             // 16384
    int D = in_sizes[0] / N;         // 128 (D4 = 32 hard-wired in kernel)

    float* out       = (float*)d_out;
    float* valid_out = out + (size_t)3 * N * D;  // tail of d_out: [N] valid mask

    int nblk = (N * 64 + BLOCK - 1) / BLOCK;     // one wave per anchor
    triplet_fused_kernel<<<nblk, BLOCK, 0, stream>>>(
        labels, (const f32x4*)emb, (f32x4*)out, valid_out, N);
}

// Round 10
// 15.310 us; speedup vs baseline: 1.7738x; 1.0283x over previous
//
#include <hip/hip_runtime.h>

typedef float f32x4 __attribute__((ext_vector_type(4)));

#define BLOCK 256   // 4 waves per block, one anchor per wave

// Fused triplet miner: ONE WAVE per anchor, minimized serial chain.
//  - lane reads 8 CONTIGUOUS labels (2x int4 at chunks kbase+2*lane, +1),
//    512 labels/iteration, 2-deep register prefetch.
//  - per iteration: 8 compares -> 8-bit mask -> TWO ballots -> branch.
//  - match masks captured at ballot time; post-loop resolve is shfl+ffs
//    (no reloads on the critical chain).
//  - anchor emb row loaded BEFORE mining (latency hidden under the scan);
//    pos+neg rows fetched with one combined instruction afterwards.
//  - NORMAL stores (through L2): L2 write-combines the 25 MB stream into
//    full lines; NT direct-to-HBM 16B stores were the suspected 2x loss.
__global__ void __launch_bounds__(BLOCK) triplet_fused_kernel(
    const int* __restrict__ labels,
    const f32x4* __restrict__ emb,    // [N][32]
    f32x4* __restrict__ out,          // [3][N][32]
    float* __restrict__ valid_out,    // [N]
    int N) {

    const int D4 = 32;
    int lane = threadIdx.x & 63;
    int i = blockIdx.x * (BLOCK >> 6) + (threadIdx.x >> 6);   // anchor (wave-uniform)
    if (i >= N) return;

    // Early independent loads: anchor label + anchor embedding row.
    int d4 = lane & 31;
    f32x4 ea = emb[(size_t)i * D4 + d4];   // row i (L1 broadcast across lanes)
    int my = labels[i];

    const int4* lab4 = (const int4*)labels;
    int nq = N >> 2;                       // N % 4 == 0

    int kb0 = (i + 1) >> 2;                // first chunk containing j > i

    // First-iteration validity mask: only lane 0's first chunk can hold j <= i.
    unsigned mv_first = 0xFFu;
    if (lane == 0) {
        int j0 = kb0 << 2;
        int nclr = i - j0 + 1;             // leading labels with j <= i (0..3)
        if (nclr > 0) mv_first &= (0xFFu << nclr);
    }

    int kbase = kb0;
    bool fp = false, fn = false;
    unsigned long long balp = 0, baln = 0;
    int basep = 0, basen = 0;
    unsigned msp = 0, msn = 0;             // captured masked match masks

    // 2-deep prefetch (clamped addresses; masked by mv in processing).
    int4 a0 = lab4[min(kbase + 2 * lane,     nq - 1)];
    int4 b0 = lab4[min(kbase + 2 * lane + 1, nq - 1)];
    int4 a1 = lab4[min(kbase + 128 + 2 * lane,     nq - 1)];
    int4 b1 = lab4[min(kbase + 128 + 2 * lane + 1, nq - 1)];

    unsigned mv_iter = mv_first;
    if (kbase < nq) {
        while (true) {
            int4 a2 = lab4[min(kbase + 256 + 2 * lane,     nq - 1)];
            int4 b2 = lab4[min(kbase + 256 + 2 * lane + 1, nq - 1)];

            int kq0 = kbase + 2 * lane, kq1 = kq0 + 1;
            unsigned mv = mv_iter;
            if (kq0 >= nq)      mv = 0;
            else if (kq1 >= nq) mv &= 0x0Fu;

            unsigned ms = (a0.x == my ?   1u : 0u) | (a0.y == my ?   2u : 0u)
                        | (a0.z == my ?   4u : 0u) | (a0.w == my ?   8u : 0u)
                        | (b0.x == my ?  16u : 0u) | (b0.y == my ?  32u : 0u)
                        | (b0.z == my ?  64u : 0u) | (b0.w == my ? 128u : 0u);

            unsigned mp = ms & mv;
            unsigned mn = (~ms) & mv;
            unsigned long long bp = __ballot(mp != 0u);
            unsigned long long bn = __ballot(mn != 0u);
            if (!fp && bp) { fp = true; balp = bp; basep = kbase; msp = mp; }
            if (!fn && bn) { fn = true; baln = bn; basen = kbase; msn = mn; }

            kbase += 128;
            if ((fp && fn) || kbase >= nq) break;
            a0 = a1; b0 = b1; a1 = a2; b1 = b2;
            mv_iter = 0xFFu;
        }
    }

    // Resolve exact indices: pure ALU + shfl (no memory on the chain).
    int p = 0, ng = 0;
    if (fp) {
        int ls = (int)__ffsll(balp) - 1;
        unsigned m = __shfl(msp, ls);
        p = ((basep + 2 * ls) << 2) + (__ffs(m) - 1);
    }
    if (fn) {
        int ls = (int)__ffsll(baln) - 1;
        unsigned m = __shfl(msn, ls);
        ng = ((basen + 2 * ls) << 2) + (__ffs(m) - 1);
    }

    float v = (fp && fn) ? 1.0f : 0.0f;

    // Combined gather: lanes<32 -> neg row, lanes>=32 -> pos row (one instr).
    size_t ND4 = (size_t)N * D4;
    int gsrc = (lane < 32) ? ng : p;
    f32x4 eg = emb[(size_t)gsrc * D4 + d4];

    if (lane == 0) valid_out[i] = v;

    // Pass 1: lanes<32 store anchor row (t=0), lanes>=32 store pos row (t=1).
    int   t  = lane >> 5;
    f32x4 r0 = (lane < 32) ? ea : eg;
    out[(size_t)t * ND4 + (size_t)i * D4 + d4] = r0 * v;

    // Pass 2: lanes<32 store neg row (t=2).
    if (lane < 32)
        out[2 * ND4 + (size_t)i * D4 + d4] = eg * v;
}

extern "C" void kernel_launch(void* const* d_in, const int* in_sizes, int n_in,
                              void* d_out, int out_size, void* d_ws, size_t ws_size,
                              hipStream_t stream) {
    const float* emb    = (const float*)d_in[0];
    const int*   labels = (const int*)d_in[1];   // harness passes integers as int32

    int N = in_sizes[1];             // 16384
    int D = in_sizes[0] / N;         // 128 (D4 = 32 hard-wired in kernel)

    float* out       = (float*)d_out;
    float* valid_out = out + (size_t)3 * N * D;  // tail of d_out: [N] valid mask

    int nblk = (N * 64 + BLOCK - 1) / BLOCK;     // one wave per anchor
    triplet_fused_kernel<<<nblk, BLOCK, 0, stream>>>(
        labels, (const f32x4*)emb, (f32x4*)out, valid_out, N);
}